// Round 1
// baseline (259.204 us; speedup 1.0000x reference)
//
#include <hip/hip_runtime.h>
#include <stdint.h>

#define B_N   16384
#define NREG  64
#define KNB   5
#define TILE  1024
#define QPB   8                      // queries per 256-thread block (4 waves x 2)
#define NBLK_SP (B_N / QPB)          // 2048

static __device__ __forceinline__ unsigned long long u64min(unsigned long long a,
                                                            unsigned long long b) {
    return a < b ? a : b;
}

static __device__ __forceinline__ unsigned long long shfl_xor_u64(unsigned long long v, int m) {
    int lo = __shfl_xor((int)(unsigned)(v & 0xffffffffull), m, 64);
    int hi = __shfl_xor((int)(unsigned)(v >> 32), m, 64);
    return ((unsigned long long)(unsigned)hi << 32) | (unsigned)lo;
}

#define CE(a, b)                                   \
    do {                                           \
        unsigned long long _lo = u64min(a, b);     \
        unsigned long long _hi = (a < b) ? b : a;  \
        a = _lo;                                   \
        b = _hi;                                   \
    } while (0)

// ---------------- region loss: one block per region, no atomics ----------------
__global__ __launch_bounds__(256) void region_kernel(const float* __restrict__ c,
                                                     const int* __restrict__ ids,
                                                     float* __restrict__ wsreg) {
    const int r = blockIdx.x;
    const int tid = threadIdx.x;
    float cnt = 0.f, sx = 0.f, sy = 0.f, sz = 0.f, sxx = 0.f, syy = 0.f, szz = 0.f;
    for (int i = tid; i < B_N; i += 256) {
        int id = ids[i];
        float m = (id == r) ? 1.0f : 0.0f;
        float x = c[3 * i + 0], y = c[3 * i + 1], z = c[3 * i + 2];
        cnt += m;
        sx += m * x;  sy += m * y;  sz += m * z;
        sxx += m * x * x;  syy += m * y * y;  szz += m * z * z;
    }
    for (int off = 32; off > 0; off >>= 1) {
        cnt += __shfl_down(cnt, off);
        sx  += __shfl_down(sx, off);
        sy  += __shfl_down(sy, off);
        sz  += __shfl_down(sz, off);
        sxx += __shfl_down(sxx, off);
        syy += __shfl_down(syy, off);
        szz += __shfl_down(szz, off);
    }
    __shared__ float sb[4][7];
    const int lane = tid & 63, w = tid >> 6;
    if (lane == 0) {
        sb[w][0] = cnt; sb[w][1] = sx; sb[w][2] = sy; sb[w][3] = sz;
        sb[w][4] = sxx; sb[w][5] = syy; sb[w][6] = szz;
    }
    __syncthreads();
    if (tid == 0) {
        float C = 0, SX = 0, SY = 0, SZ = 0, SXX = 0, SYY = 0, SZZ = 0;
        for (int i = 0; i < 4; i++) {
            C += sb[i][0]; SX += sb[i][1]; SY += sb[i][2]; SZ += sb[i][3];
            SXX += sb[i][4]; SYY += sb[i][5]; SZZ += sb[i][6];
        }
        float safe = fmaxf(C, 1.0f);
        float mx = SX / safe, my = SY / safe, mz = SZ / safe;
        float ssc = (SXX - C * mx * mx) + (SYY - C * my * my) + (SZZ - C * mz * mz);
        float npairs = C * (C - 1.0f) * 0.5f;
        float denom = fmaxf(npairs, 1.0f) * 3.0f;
        float per = (C > 1.0f) ? (2.0f * ssc / denom) : 0.0f;
        wsreg[r] = per;
    }
}

// ---------------- spatial KNN loss: 32 lanes per query ----------------
__global__ __launch_bounds__(256) void spatial_kernel(const float* __restrict__ c,
                                                      const float* __restrict__ x,
                                                      float* __restrict__ part) {
    __shared__ float xs[TILE], ys[TILE], zs[TILE];
    __shared__ float qsum[QPB];
    const int tid = threadIdx.x;
    const int lane = tid & 63;
    const int w = tid >> 6;      // wave 0..3
    const int sub = lane >> 5;   // 0/1: which query in this wave
    const int sl = lane & 31;    // lane within query group
    const int q = blockIdx.x * QPB + w * 2 + sub;

    const float qx = x[3 * q + 0], qy = x[3 * q + 1], qz = x[3 * q + 2];

    unsigned long long s0 = ~0ull, s1 = ~0ull, s2 = ~0ull, s3 = ~0ull, s4 = ~0ull;

    for (int t0 = 0; t0 < B_N; t0 += TILE) {
        __syncthreads();
#pragma unroll
        for (int k = 0; k < TILE / 256; k++) {
            int jj = tid + 256 * k;
            int j = t0 + jj;
            xs[jj] = x[3 * j + 0];
            ys[jj] = x[3 * j + 1];
            zs[jj] = x[3 * j + 2];
        }
        __syncthreads();
#pragma unroll 4
        for (int u = 0; u < TILE / 32; u++) {
            int jj = sl + 32 * u;
            float dx = qx - xs[jj];
            float dy = qy - ys[jj];
            float dz = qz - zs[jj];
            float d = dx * dx + dy * dy + dz * dz;
            int j = t0 + jj;
            unsigned long long key =
                ((unsigned long long)__float_as_uint(d) << 32) | (unsigned)j;
            if (j == q) key = ~0ull;  // self-exclusion
            if (key < s4) {           // sorted insert (lexicographic (d, idx))
                s4 = key;
                unsigned long long t;
                if (s4 < s3) { t = s3; s3 = s4; s4 = t; }
                if (s3 < s2) { t = s2; s2 = s3; s3 = t; }
                if (s2 < s1) { t = s1; s1 = s2; s2 = t; }
                if (s1 < s0) { t = s0; s0 = s1; s1 = t; }
            }
        }
    }

    // butterfly merge of sorted 5-lists across the 32-lane group
    for (int m = 1; m <= 16; m <<= 1) {
        unsigned long long b0 = shfl_xor_u64(s0, m);
        unsigned long long b1 = shfl_xor_u64(s1, m);
        unsigned long long b2 = shfl_xor_u64(s2, m);
        unsigned long long b3 = shfl_xor_u64(s3, m);
        unsigned long long b4 = shfl_xor_u64(s4, m);
        // bitonic half-cleaner: keep 5 smallest of the union
        s0 = u64min(s0, b4);
        s1 = u64min(s1, b3);
        s2 = u64min(s2, b2);
        s3 = u64min(s3, b1);
        s4 = u64min(s4, b0);
        // re-sort ascending (general 9-comparator network for 5 elements)
        CE(s0, s1); CE(s3, s4); CE(s2, s4); CE(s2, s3); CE(s1, s4);
        CE(s0, s3); CE(s0, s2); CE(s1, s3); CE(s1, s2);
    }

    if (sl == 0) {
        float cx = c[3 * q + 0], cy = c[3 * q + 1], cz = c[3 * q + 2];
        float acc = 0.f;
        unsigned long long ks[5] = {s0, s1, s2, s3, s4};
#pragma unroll
        for (int n = 0; n < KNB; n++) {
            int nb = (int)(unsigned)(ks[n] & 0xffffffffull);
            float dx = cx - c[3 * nb + 0];
            float dy = cy - c[3 * nb + 1];
            float dz = cz - c[3 * nb + 2];
            acc += dx * dx + dy * dy + dz * dz;
        }
        qsum[w * 2 + sub] = acc;
    }
    __syncthreads();
    if (tid == 0) {
        float s = 0.f;
        for (int i = 0; i < QPB; i++) s += qsum[i];
        part[blockIdx.x] = s;
    }
}

// ---------------- finalize ----------------
__global__ __launch_bounds__(256) void finalize_kernel(const float* __restrict__ wsreg,
                                                       const float* __restrict__ part,
                                                       float* __restrict__ out) {
    const int tid = threadIdx.x;
    float s = 0.f;
    for (int i = tid; i < NBLK_SP; i += 256) s += part[i];
    float r = (tid < NREG) ? wsreg[tid] : 0.f;
    for (int off = 32; off > 0; off >>= 1) {
        s += __shfl_down(s, off);
        r += __shfl_down(r, off);
    }
    __shared__ float sb[4];
    const int lane = tid & 63, w = tid >> 6;
    if (lane == 0) sb[w] = s;
    __syncthreads();
    if (tid == 0) {
        float S = sb[0] + sb[1] + sb[2] + sb[3];
        float spatial_mean = S / (float)(B_N * KNB);
        out[0] = 0.02f * r + 0.0005f * (spatial_mean / 3.0f);
    }
}

extern "C" void kernel_launch(void* const* d_in, const int* in_sizes, int n_in,
                              void* d_out, int out_size, void* d_ws, size_t ws_size,
                              hipStream_t stream) {
    const float* c  = (const float*)d_in[0];   // c_points   [16384,3] f32
    const float* xs = (const float*)d_in[1];   // coords_std [16384,3] f32
    const int* ids  = (const int*)d_in[2];     // region_ids [16384] i32
    float* out = (float*)d_out;
    float* ws = (float*)d_ws;
    float* wsreg = ws;          // 64 floats
    float* wspart = ws + 64;    // 2048 floats

    hipLaunchKernelGGL(region_kernel, dim3(NREG), dim3(256), 0, stream, c, ids, wsreg);
    hipLaunchKernelGGL(spatial_kernel, dim3(NBLK_SP), dim3(256), 0, stream, c, xs, wspart);
    hipLaunchKernelGGL(finalize_kernel, dim3(1), dim3(256), 0, stream, wsreg, wspart, out);
}

// Round 2
// 248.150 us; speedup vs baseline: 1.0445x; 1.0445x over previous
//
#include <hip/hip_runtime.h>
#include <stdint.h>

#define B_N      16384
#define NREG     64
#define KNB      5
#define S_CHUNKS 8
#define CHUNK_L  (B_N / S_CHUNKS)        // 2048
#define QPB      256                     // queries per spatial block
#define QBLKS    (B_N / QPB)             // 64
#define SP_BLOCKS (QBLKS * S_CHUNKS)     // 512
#define NCAND    (S_CHUNKS * KNB)        // 40 candidates per query

static __device__ __forceinline__ float inf32() { return __int_as_float(0x7f800000); }

// ---------------- precompute pre[j] = (-2x, -2y, -2z, |x|^2) ----------------
__global__ __launch_bounds__(256) void pre_kernel(const float* __restrict__ x,
                                                  float4* __restrict__ pre) {
    int j = blockIdx.x * 256 + threadIdx.x;
    float jx = x[3 * j + 0], jy = x[3 * j + 1], jz = x[3 * j + 2];
    pre[j] = make_float4(-2.f * jx, -2.f * jy, -2.f * jz, jx * jx + jy * jy + jz * jz);
}

// ---------------- region loss: one block per region, no atomics ----------------
__global__ __launch_bounds__(256) void region_kernel(const float* __restrict__ c,
                                                     const int* __restrict__ ids,
                                                     float* __restrict__ wsreg) {
    const int r = blockIdx.x;
    const int tid = threadIdx.x;
    float cnt = 0.f, sx = 0.f, sy = 0.f, sz = 0.f, sxx = 0.f, syy = 0.f, szz = 0.f;
    for (int i = tid; i < B_N; i += 256) {
        int id = ids[i];
        float m = (id == r) ? 1.0f : 0.0f;
        float x = c[3 * i + 0], y = c[3 * i + 1], z = c[3 * i + 2];
        cnt += m;
        sx += m * x;  sy += m * y;  sz += m * z;
        sxx += m * x * x;  syy += m * y * y;  szz += m * z * z;
    }
    for (int off = 32; off > 0; off >>= 1) {
        cnt += __shfl_down(cnt, off);
        sx  += __shfl_down(sx, off);
        sy  += __shfl_down(sy, off);
        sz  += __shfl_down(sz, off);
        sxx += __shfl_down(sxx, off);
        syy += __shfl_down(syy, off);
        szz += __shfl_down(szz, off);
    }
    __shared__ float sb[4][7];
    const int lane = tid & 63, w = tid >> 6;
    if (lane == 0) {
        sb[w][0] = cnt; sb[w][1] = sx; sb[w][2] = sy; sb[w][3] = sz;
        sb[w][4] = sxx; sb[w][5] = syy; sb[w][6] = szz;
    }
    __syncthreads();
    if (tid == 0) {
        float C = 0, SX = 0, SY = 0, SZ = 0, SXX = 0, SYY = 0, SZZ = 0;
        for (int i = 0; i < 4; i++) {
            C += sb[i][0]; SX += sb[i][1]; SY += sb[i][2]; SZ += sb[i][3];
            SXX += sb[i][4]; SYY += sb[i][5]; SZZ += sb[i][6];
        }
        float safe = fmaxf(C, 1.0f);
        float mx = SX / safe, my = SY / safe, mz = SZ / safe;
        float ssc = (SXX - C * mx * mx) + (SYY - C * my * my) + (SZZ - C * mz * mz);
        float npairs = C * (C - 1.0f) * 0.5f;
        float denom = fmaxf(npairs, 1.0f) * 3.0f;
        wsreg[r] = (C > 1.0f) ? (2.0f * ssc / denom) : 0.0f;
    }
}

// ---------------- spatial KNN scan: lane-per-query, uniform j (scalar loads) ----------------
__global__ __launch_bounds__(256) void spatial_kernel(const float* __restrict__ x,
                                                      const float4* __restrict__ pre,
                                                      unsigned short* __restrict__ idxbuf) {
    const int tid = threadIdx.x;
    const int qb = blockIdx.x & (QBLKS - 1);   // query block 0..63
    const int chunk = blockIdx.x >> 6;         // j-chunk 0..7
    const int q = qb * QPB + tid;

    const float qx = x[3 * q + 0], qy = x[3 * q + 1], qz = x[3 * q + 2];

    float s0 = inf32(), s1 = inf32(), s2 = inf32(), s3 = inf32(), s4 = inf32();
    int i0 = 0, i1 = 0, i2 = 0, i3 = 0, i4 = 0;

    const int jbase = chunk * CHUNK_L;
    for (int jb = jbase; jb < jbase + CHUNK_L; jb += 8) {
#pragma unroll
        for (int u = 0; u < 8; ++u) {
            const int j = jb + u;              // wave-uniform -> s_load of pre[j]
            const float4 pj = pre[j];
            float dt = pj.w;
            dt = fmaf(pj.x, qx, dt);
            dt = fmaf(pj.y, qy, dt);
            dt = fmaf(pj.z, qz, dt);
            bool pr = dt < s4;                 // 1 VALU cmp; rest is rare path
            if (__any(pr)) {
                bool p = pr && (j != q);       // self-exclusion only in rare path
                float nv = p ? dt : inf32();
                bool c4 = nv < s4, c3 = nv < s3, c2 = nv < s2, c1 = nv < s1, c0 = nv < s0;
                s4 = c3 ? s3 : (c4 ? nv : s4);  i4 = c3 ? i3 : (c4 ? j : i4);
                s3 = c2 ? s2 : (c3 ? nv : s3);  i3 = c2 ? i2 : (c3 ? j : i3);
                s2 = c1 ? s1 : (c2 ? nv : s2);  i2 = c1 ? i1 : (c2 ? j : i2);
                s1 = c0 ? s0 : (c1 ? nv : s1);  i1 = c0 ? i0 : (c1 ? j : i1);
                s0 = c0 ? nv : s0;              i0 = c0 ? j : i0;
            }
        }
    }

    unsigned short* w = idxbuf + (size_t)q * NCAND + chunk * KNB;
    w[0] = (unsigned short)i0; w[1] = (unsigned short)i1; w[2] = (unsigned short)i2;
    w[3] = (unsigned short)i3; w[4] = (unsigned short)i4;
}

// ---------------- merge 8 chunk-top5 -> global top5, compute c-loss ----------------
__global__ __launch_bounds__(256) void merge_kernel(const float* __restrict__ x,
                                                    const float* __restrict__ c,
                                                    const float4* __restrict__ pre,
                                                    const unsigned short* __restrict__ idxbuf,
                                                    float* __restrict__ spart) {
    const int tid = threadIdx.x;
    const int q = blockIdx.x * 256 + tid;
    const float qx = x[3 * q + 0], qy = x[3 * q + 1], qz = x[3 * q + 2];

    float s0 = inf32(), s1 = inf32(), s2 = inf32(), s3 = inf32(), s4 = inf32();
    int i0 = 0, i1 = 0, i2 = 0, i3 = 0, i4 = 0;

#pragma unroll
    for (int t = 0; t < NCAND; ++t) {
        int cand = (int)idxbuf[(size_t)q * NCAND + t];
        float4 pj = pre[cand];
        float nv = pj.w;
        nv = fmaf(pj.x, qx, nv);
        nv = fmaf(pj.y, qy, nv);
        nv = fmaf(pj.z, qz, nv);
        bool c4 = nv < s4, c3 = nv < s3, c2 = nv < s2, c1 = nv < s1, c0 = nv < s0;
        s4 = c3 ? s3 : (c4 ? nv : s4);  i4 = c3 ? i3 : (c4 ? cand : i4);
        s3 = c2 ? s2 : (c3 ? nv : s3);  i3 = c2 ? i2 : (c3 ? cand : i3);
        s2 = c1 ? s1 : (c2 ? nv : s2);  i2 = c1 ? i1 : (c2 ? cand : i2);
        s1 = c0 ? s0 : (c1 ? nv : s1);  i1 = c0 ? i0 : (c1 ? cand : i1);
        s0 = c0 ? nv : s0;              i0 = c0 ? cand : i0;
    }

    const float cx = c[3 * q + 0], cy = c[3 * q + 1], cz = c[3 * q + 2];
    float acc = 0.f;
    int ks[5] = {i0, i1, i2, i3, i4};
#pragma unroll
    for (int n = 0; n < KNB; ++n) {
        int nb = ks[n];
        float dx = cx - c[3 * nb + 0];
        float dy = cy - c[3 * nb + 1];
        float dz = cz - c[3 * nb + 2];
        acc += dx * dx + dy * dy + dz * dz;
    }

    for (int off = 32; off > 0; off >>= 1) acc += __shfl_down(acc, off);
    __shared__ float sb[4];
    const int lane = tid & 63, w = tid >> 6;
    if (lane == 0) sb[w] = acc;
    __syncthreads();
    if (tid == 0) spart[blockIdx.x] = sb[0] + sb[1] + sb[2] + sb[3];
}

// ---------------- finalize ----------------
__global__ __launch_bounds__(256) void finalize_kernel(const float* __restrict__ wsreg,
                                                       const float* __restrict__ spart,
                                                       float* __restrict__ out) {
    const int tid = threadIdx.x;
    float s = (tid < QBLKS) ? spart[tid] : 0.f;
    float r = (tid < NREG) ? wsreg[tid] : 0.f;
    for (int off = 32; off > 0; off >>= 1) {
        s += __shfl_down(s, off);
        r += __shfl_down(r, off);
    }
    __shared__ float sb[4][2];
    const int lane = tid & 63, w = tid >> 6;
    if (lane == 0) { sb[w][0] = s; sb[w][1] = r; }
    __syncthreads();
    if (tid == 0) {
        float S = sb[0][0] + sb[1][0] + sb[2][0] + sb[3][0];
        float R = sb[0][1] + sb[1][1] + sb[2][1] + sb[3][1];
        float spatial_mean = S / (float)(B_N * KNB);
        out[0] = 0.02f * R + 0.0005f * (spatial_mean / 3.0f);
    }
}

extern "C" void kernel_launch(void* const* d_in, const int* in_sizes, int n_in,
                              void* d_out, int out_size, void* d_ws, size_t ws_size,
                              hipStream_t stream) {
    const float* c  = (const float*)d_in[0];   // c_points   [16384,3] f32
    const float* xs = (const float*)d_in[1];   // coords_std [16384,3] f32
    const int* ids  = (const int*)d_in[2];     // region_ids [16384] i32
    float* out = (float*)d_out;

    char* ws = (char*)d_ws;
    float4* pre = (float4*)ws;                                   // 16384*16 B = 256 KiB
    unsigned short* idxbuf = (unsigned short*)(ws + (size_t)B_N * 16);  // 16384*40*2 B = 1.25 MiB
    float* wsreg = (float*)(ws + (size_t)B_N * 16 + (size_t)B_N * NCAND * 2);  // 64 f
    float* spart = wsreg + NREG;                                 // 64 f

    hipLaunchKernelGGL(pre_kernel, dim3(B_N / 256), dim3(256), 0, stream, xs, pre);
    hipLaunchKernelGGL(region_kernel, dim3(NREG), dim3(256), 0, stream, c, ids, wsreg);
    hipLaunchKernelGGL(spatial_kernel, dim3(SP_BLOCKS), dim3(256), 0, stream, xs, pre, idxbuf);
    hipLaunchKernelGGL(merge_kernel, dim3(QBLKS), dim3(256), 0, stream, xs, c, pre, idxbuf, spart);
    hipLaunchKernelGGL(finalize_kernel, dim3(1), dim3(256), 0, stream, wsreg, spart, out);
}

// Round 3
// 146.439 us; speedup vs baseline: 1.7700x; 1.6946x over previous
//
#include <hip/hip_runtime.h>
#include <stdint.h>

#define B_N      16384
#define NREG     64
#define KNB      5

#define SAMPLE   2048
#define NSUB     16
#define SUBLEN   (SAMPLE / NSUB)             // 128

#define NCHUNK   28
#define CHUNKLEN ((B_N - SAMPLE) / NCHUNK)   // 512
#define QPB      256
#define QBLKS    (B_N / QPB)                 // 64

#define SLOTS    (KNB + NCHUNK * KNB)        // 145 candidate slots per query
#define SENT     0xFFFF

static __device__ __forceinline__ float inf32() { return __int_as_float(0x7f800000); }

// flat 5-slot sorted-insert (ascending), tracking indices
#define INS5(nv, jj)                                                        \
    {                                                                       \
        bool c4 = (nv) < s4, c3 = (nv) < s3, c2 = (nv) < s2,                \
             c1 = (nv) < s1, c0 = (nv) < s0;                                \
        s4 = c3 ? s3 : (c4 ? (nv) : s4);  i4 = c3 ? i3 : (c4 ? (jj) : i4);  \
        s3 = c2 ? s2 : (c3 ? (nv) : s3);  i3 = c2 ? i2 : (c3 ? (jj) : i3);  \
        s2 = c1 ? s1 : (c2 ? (nv) : s2);  i2 = c1 ? i1 : (c2 ? (jj) : i2);  \
        s1 = c0 ? s0 : (c1 ? (nv) : s1);  i1 = c0 ? i0 : (c1 ? (jj) : i1);  \
        s0 = c0 ? (nv) : s0;              i0 = c0 ? (jj) : i0;              \
    }

// ---------------- pre[j] = (-2x, -2y, -2z, |x|^2) ----------------
__global__ __launch_bounds__(256) void pre_kernel(const float* __restrict__ x,
                                                  float4* __restrict__ pre) {
    int j = blockIdx.x * 256 + threadIdx.x;
    float jx = x[3 * j + 0], jy = x[3 * j + 1], jz = x[3 * j + 2];
    pre[j] = make_float4(-2.f * jx, -2.f * jy, -2.f * jz, jx * jx + jy * jy + jz * jz);
}

// ---------------- region loss: one block per region ----------------
__global__ __launch_bounds__(256) void region_kernel(const float* __restrict__ c,
                                                     const int* __restrict__ ids,
                                                     float* __restrict__ wsreg) {
    const int r = blockIdx.x;
    const int tid = threadIdx.x;
    float cnt = 0.f, sx = 0.f, sy = 0.f, sz = 0.f, sxx = 0.f, syy = 0.f, szz = 0.f;
    for (int i = tid; i < B_N; i += 256) {
        int id = ids[i];
        float m = (id == r) ? 1.0f : 0.0f;
        float x = c[3 * i + 0], y = c[3 * i + 1], z = c[3 * i + 2];
        cnt += m;
        sx += m * x;  sy += m * y;  sz += m * z;
        sxx += m * x * x;  syy += m * y * y;  szz += m * z * z;
    }
    for (int off = 32; off > 0; off >>= 1) {
        cnt += __shfl_down(cnt, off);
        sx  += __shfl_down(sx, off);
        sy  += __shfl_down(sy, off);
        sz  += __shfl_down(sz, off);
        sxx += __shfl_down(sxx, off);
        syy += __shfl_down(syy, off);
        szz += __shfl_down(szz, off);
    }
    __shared__ float sb[4][7];
    const int lane = tid & 63, w = tid >> 6;
    if (lane == 0) {
        sb[w][0] = cnt; sb[w][1] = sx; sb[w][2] = sy; sb[w][3] = sz;
        sb[w][4] = sxx; sb[w][5] = syy; sb[w][6] = szz;
    }
    __syncthreads();
    if (tid == 0) {
        float C = 0, SX = 0, SY = 0, SZ = 0, SXX = 0, SYY = 0, SZZ = 0;
        for (int i = 0; i < 4; i++) {
            C += sb[i][0]; SX += sb[i][1]; SY += sb[i][2]; SZ += sb[i][3];
            SXX += sb[i][4]; SYY += sb[i][5]; SZZ += sb[i][6];
        }
        float safe = fmaxf(C, 1.0f);
        float mx = SX / safe, my = SY / safe, mz = SZ / safe;
        float ssc = (SXX - C * mx * mx) + (SYY - C * my * my) + (SZZ - C * mz * mz);
        float npairs = C * (C - 1.0f) * 0.5f;
        float denom = fmaxf(npairs, 1.0f) * 3.0f;
        wsreg[r] = (C > 1.0f) ? (2.0f * ssc / denom) : 0.0f;
    }
}

// ---------------- sample scan: top-5 per (query, subchunk), unconditional insert ----------------
__global__ __launch_bounds__(256) void tau_scan_kernel(const float* __restrict__ x,
                                                       const float4* __restrict__ pre,
                                                       unsigned short* __restrict__ idxbuf) {
    const int tid = threadIdx.x;
    const int qb = blockIdx.x & (QBLKS - 1);
    const int sub = blockIdx.x >> 6;          // 0..15
    const int q = qb * QPB + tid;
    const float qx = x[3 * q + 0], qy = x[3 * q + 1], qz = x[3 * q + 2];

    float s0 = inf32(), s1 = inf32(), s2 = inf32(), s3 = inf32(), s4 = inf32();
    int i0 = 0, i1 = 0, i2 = 0, i3 = 0, i4 = 0;

    const int j0 = sub * SUBLEN;
    for (int jb = j0; jb < j0 + SUBLEN; jb += 8) {
        float dt[8];
#pragma unroll
        for (int u = 0; u < 8; ++u) {
            float4 pj = pre[jb + u];          // wave-uniform address -> scalar loads
            dt[u] = fmaf(pj.x, qx, fmaf(pj.y, qy, fmaf(pj.z, qz, pj.w)));
        }
#pragma unroll
        for (int u = 0; u < 8; ++u) {
            int j = jb + u;
            float nv = (j != q) ? dt[u] : inf32();   // self-exclusion
            INS5(nv, j);
        }
    }
    unsigned short* w = idxbuf + (size_t)q * SLOTS + KNB + sub * KNB;
    w[0] = (unsigned short)i0; w[1] = (unsigned short)i1; w[2] = (unsigned short)i2;
    w[3] = (unsigned short)i3; w[4] = (unsigned short)i4;
}

// ---------------- merge sample candidates -> tau[q] + seed top-5 ----------------
__global__ __launch_bounds__(256) void tau_merge_kernel(const float* __restrict__ x,
                                                        const float4* __restrict__ pre,
                                                        unsigned short* __restrict__ idxbuf,
                                                        float* __restrict__ tau) {
    const int tid = threadIdx.x;
    const int q = blockIdx.x * 256 + tid;
    const float qx = x[3 * q + 0], qy = x[3 * q + 1], qz = x[3 * q + 2];

    float s0 = inf32(), s1 = inf32(), s2 = inf32(), s3 = inf32(), s4 = inf32();
    int i0 = 0, i1 = 0, i2 = 0, i3 = 0, i4 = 0;

    const unsigned short* t = idxbuf + (size_t)q * SLOTS + KNB;
#pragma unroll 8
    for (int n = 0; n < NSUB * KNB; ++n) {
        int cand = (int)t[n];
        float4 pj = pre[cand];
        float nv = fmaf(pj.x, qx, fmaf(pj.y, qy, fmaf(pj.z, qz, pj.w)));
        INS5(nv, cand);
    }
    tau[q] = s4;
    unsigned short* w = idxbuf + (size_t)q * SLOTS;
    w[0] = (unsigned short)i0; w[1] = (unsigned short)i1; w[2] = (unsigned short)i2;
    w[3] = (unsigned short)i3; w[4] = (unsigned short)i4;
}

// ---------------- filtered scan of remaining points, seeded with tau ----------------
__global__ __launch_bounds__(256) void spatial_kernel(const float* __restrict__ x,
                                                      const float4* __restrict__ pre,
                                                      const float* __restrict__ tau,
                                                      unsigned short* __restrict__ idxbuf) {
    const int tid = threadIdx.x;
    const int qb = blockIdx.x & (QBLKS - 1);
    const int chunk = blockIdx.x >> 6;        // 0..27
    const int q = qb * QPB + tid;
    const float qx = x[3 * q + 0], qy = x[3 * q + 1], qz = x[3 * q + 2];

    const float t = tau[q];
    float s0 = t, s1 = t, s2 = t, s3 = t, s4 = t;   // tau-seeded: filter is (dt < s4)
    int i0 = SENT, i1 = SENT, i2 = SENT, i3 = SENT, i4 = SENT;

    const int jbase = SAMPLE + chunk * CHUNKLEN;
    for (int jb = jbase; jb < jbase + CHUNKLEN; jb += 8) {
        float dt[8];
#pragma unroll
        for (int u = 0; u < 8; ++u) {
            float4 pj = pre[jb + u];          // wave-uniform address -> scalar loads
            dt[u] = fmaf(pj.x, qx, fmaf(pj.y, qy, fmaf(pj.z, qz, pj.w)));
        }
#pragma unroll
        for (int u = 0; u < 8; ++u) {
            if (__any(dt[u] < s4)) {          // rare (~18%) correlated branch
                int j = jb + u;
                bool p = (dt[u] < s4) && (j != q);
                float nv = p ? dt[u] : inf32();
                INS5(nv, j);
            }
        }
    }
    unsigned short* w = idxbuf + (size_t)q * SLOTS + KNB + chunk * KNB;
    w[0] = (unsigned short)i0; w[1] = (unsigned short)i1; w[2] = (unsigned short)i2;
    w[3] = (unsigned short)i3; w[4] = (unsigned short)i4;
}

// ---------------- final merge: exact top-5 of <=145 candidates + c-loss ----------------
__global__ __launch_bounds__(256) void merge_kernel(const float* __restrict__ x,
                                                    const float* __restrict__ c,
                                                    const float4* __restrict__ pre,
                                                    const unsigned short* __restrict__ idxbuf,
                                                    float* __restrict__ spart) {
    const int tid = threadIdx.x;
    const int q = blockIdx.x * 256 + tid;
    const float qx = x[3 * q + 0], qy = x[3 * q + 1], qz = x[3 * q + 2];

    float s0 = inf32(), s1 = inf32(), s2 = inf32(), s3 = inf32(), s4 = inf32();
    int i0 = 0, i1 = 0, i2 = 0, i3 = 0, i4 = 0;

    const unsigned short* t = idxbuf + (size_t)q * SLOTS;
#pragma unroll 5
    for (int n = 0; n < SLOTS; ++n) {
        int cand = (int)t[n];
        int safe = cand & 0x3FFF;             // SENT -> 16383 (valid addr, masked by inf)
        float4 pj = pre[safe];
        float d = fmaf(pj.x, qx, fmaf(pj.y, qy, fmaf(pj.z, qz, pj.w)));
        float nv = (cand != SENT) ? d : inf32();
        INS5(nv, safe);
    }

    const float cx = c[3 * q + 0], cy = c[3 * q + 1], cz = c[3 * q + 2];
    float acc = 0.f;
    int ks[5] = {i0, i1, i2, i3, i4};
#pragma unroll
    for (int n = 0; n < KNB; ++n) {
        int nb = ks[n];
        float dx = cx - c[3 * nb + 0];
        float dy = cy - c[3 * nb + 1];
        float dz = cz - c[3 * nb + 2];
        acc += dx * dx + dy * dy + dz * dz;
    }

    for (int off = 32; off > 0; off >>= 1) acc += __shfl_down(acc, off);
    __shared__ float sb[4];
    const int lane = tid & 63, w = tid >> 6;
    if (lane == 0) sb[w] = acc;
    __syncthreads();
    if (tid == 0) spart[blockIdx.x] = sb[0] + sb[1] + sb[2] + sb[3];
}

// ---------------- finalize ----------------
__global__ __launch_bounds__(256) void finalize_kernel(const float* __restrict__ wsreg,
                                                       const float* __restrict__ spart,
                                                       float* __restrict__ out) {
    const int tid = threadIdx.x;
    float s = (tid < QBLKS) ? spart[tid] : 0.f;
    float r = (tid < NREG) ? wsreg[tid] : 0.f;
    for (int off = 32; off > 0; off >>= 1) {
        s += __shfl_down(s, off);
        r += __shfl_down(r, off);
    }
    __shared__ float sb[4][2];
    const int lane = tid & 63, w = tid >> 6;
    if (lane == 0) { sb[w][0] = s; sb[w][1] = r; }
    __syncthreads();
    if (tid == 0) {
        float S = sb[0][0] + sb[1][0] + sb[2][0] + sb[3][0];
        float R = sb[0][1] + sb[1][1] + sb[2][1] + sb[3][1];
        float spatial_mean = S / (float)(B_N * KNB);
        out[0] = 0.02f * R + 0.0005f * (spatial_mean / 3.0f);
    }
}

extern "C" void kernel_launch(void* const* d_in, const int* in_sizes, int n_in,
                              void* d_out, int out_size, void* d_ws, size_t ws_size,
                              hipStream_t stream) {
    const float* c  = (const float*)d_in[0];   // c_points   [16384,3] f32
    const float* xs = (const float*)d_in[1];   // coords_std [16384,3] f32
    const int* ids  = (const int*)d_in[2];     // region_ids [16384] i32
    float* out = (float*)d_out;

    char* ws = (char*)d_ws;
    float4* pre = (float4*)ws;                           // 256 KiB
    float* tau  = (float*)(ws + (size_t)B_N * 16);       // 64 KiB
    float* wsreg = tau + B_N;                            // 64 f
    float* spart = wsreg + NREG;                         // 64 f
    unsigned short* idxbuf = (unsigned short*)(spart + QBLKS);  // 16384*145*2 = 4.64 MiB

    hipLaunchKernelGGL(pre_kernel, dim3(B_N / 256), dim3(256), 0, stream, xs, pre);
    hipLaunchKernelGGL(region_kernel, dim3(NREG), dim3(256), 0, stream, c, ids, wsreg);
    hipLaunchKernelGGL(tau_scan_kernel, dim3(QBLKS * NSUB), dim3(256), 0, stream, xs, pre, idxbuf);
    hipLaunchKernelGGL(tau_merge_kernel, dim3(QBLKS), dim3(256), 0, stream, xs, pre, idxbuf, tau);
    hipLaunchKernelGGL(spatial_kernel, dim3(QBLKS * NCHUNK), dim3(256), 0, stream, xs, pre, tau, idxbuf);
    hipLaunchKernelGGL(merge_kernel, dim3(QBLKS), dim3(256), 0, stream, xs, c, pre, idxbuf, spart);
    hipLaunchKernelGGL(finalize_kernel, dim3(1), dim3(256), 0, stream, wsreg, spart, out);
}